// Round 10
// baseline (133.861 us; speedup 1.0000x reference)
//
#include <hip/hip_runtime.h>
#include <hip/hip_bf16.h>
#include <math.h>

#define NB 8
#define NN 8192
#define ND 1024
#define NH 256
#define NC 2
#define M_ALL (NB * NN)   // 65536 rows
#define BM 256            // block tile rows
#define BK 32             // K per iteration
#define NT (ND / BK)      // 32 iterations

typedef __attribute__((ext_vector_type(8))) short bf16x8;
typedef __attribute__((ext_vector_type(4))) float f32x4;

// barrier WITHOUT the compiler's vmcnt(0) drain: LDS ordering only.
#define BARRIER_LGKM() asm volatile("s_waitcnt lgkmcnt(0)\n\ts_barrier" ::: "memory")

__device__ inline unsigned short f2bf(float f) {   // RNE float -> bf16 bits
    unsigned int u = __builtin_bit_cast(unsigned int, f);
    u += 0x7FFFu + ((u >> 16) & 1u);
    return (unsigned short)(u >> 16);
}
__device__ inline float bf2f(unsigned short s) {
    unsigned int u = ((unsigned int)s) << 16;
    return __builtin_bit_cast(float, u);
}
__device__ inline unsigned int pk_bf16(float a, float b) {  // low=a, high=b
    __hip_bfloat162 t = __float22bfloat162_rn(float2{a, b});
    unsigned int r;
    __builtin_memcpy(&r, &t, 4);
    return r;
}

__device__ inline float wave_reduce_sum(float v) {
#pragma unroll
    for (int off = 32; off > 0; off >>= 1) v += __shfl_down(v, off, 64);
    return v;
}
__device__ inline float wave_reduce_max(float v) {
#pragma unroll
    for (int off = 32; off > 0; off >>= 1) v = fmaxf(v, __shfl_down(v, off, 64));
    return v;
}

// ---------------------------------------------------------------------------
// Pack Wp into bf16 (RNE), MFMA-B-fragment-contiguous:
// frag (t = kstep 0..31, f = col-frag 0..15), lane l holds
// B[k = t*32 + (l>>4)*8 + j][col = f*16 + (l&15)], j=0..7 contiguous.
// ---------------------------------------------------------------------------
__global__ void pack_kernel(const float* __restrict__ Wp,
                            unsigned short* __restrict__ hi)
{
    int idx  = blockIdx.x * 256 + threadIdx.x;   // 0..32767
    int lane = idx & 63;
    int f    = (idx >> 6) & 15;
    int t    = idx >> 10;
    int col  = f * 16 + (lane & 15);
    int k0   = t * 32 + (lane >> 4) * 8;
    size_t off = (size_t)idx * 8;
#pragma unroll
    for (int j = 0; j < 8; ++j)
        hi[off + j] = f2bf(Wp[(size_t)(k0 + j) * NH + col]);
}

// ---------------------------------------------------------------------------
// GEMM: h = silu(x @ Wp + bp) stored bf16; fused a = h @ Wa + ba.
// R7 structure: 256x256 tile, 8 waves (2 row x 4 col groups), BK=32, 32 iters.
// Single bf16 W (no lo term): pooled-softmax averaging makes the W rounding
// error negligible at the logits (see round-10 analysis).
// Per-iter order (vmcnt FIFO): B(t) -> x(t+3) issue -> MFMA (B wait leaves x
// in flight) -> dswrite x(t+1) -> lgkm-only barrier. x depth-3 reg pipeline.
// ---------------------------------------------------------------------------
__global__ __launch_bounds__(512, 2)
void gemm_kernel(const float* __restrict__ x,
                 const unsigned short* __restrict__ Bhi,
                 const float* __restrict__ bp,
                 const float* __restrict__ Wa,
                 const float* __restrict__ ba,
                 const int* __restrict__ lengths,
                 unsigned short* __restrict__ h_out,
                 float* __restrict__ a_out)
{
    __shared__ __align__(16) unsigned char lds_raw[32768];  // As dbuf 2x16KB; reused as h pass buffer
    __shared__ float a_red[4][BM];

    const int tid  = threadIdx.x;
    const int wave = tid >> 6;
    const int lane = tid & 63;
    const int wr = wave >> 2;           // 0..1: 128-row group
    const int wc = wave & 3;            // 0..3: 64-col group
    const int blk = blockIdx.x;
    const size_t row0 = (size_t)blk * BM;

    // ragged early-exit: this block's rows all beyond bag length
    const int bag   = blk >> 5;                // 32 blocks per bag
    const int lrow0 = (blk & 31) * BM;
    const int len   = lengths[bag];
    if (lrow0 >= len) return;

    // ---- staging geometry: thread -> 2 chunks of 8 floats (rows r0l, r0l+128)
    const int r0l = tid >> 2;                  // 0..127
    const int sl  = tid & 3;                   // chunk-in-row
    const float* xp0 = x + (row0 + r0l) * ND + sl * 8;
    const float* xp1 = xp0 + (size_t)128 * ND;
    const int offA = (((sl + (r0l >> 1)) & 3) << 4);   // rotated 16B slot
    char* const wb0 = (char*)lds_raw + r0l * 64 + offA;

    struct XR { float4 a0, b0, a1, b1; };
    XR gx0, gx1, gx2;
    auto issueX = [&](int t, XR& r) {
        const float4* p0 = (const float4*)(xp0 + (size_t)t * BK);
        const float4* p1 = (const float4*)(xp1 + (size_t)t * BK);
        r.a0 = p0[0]; r.b0 = p0[1];
        r.a1 = p1[0]; r.b1 = p1[1];
    };
    auto dswrite = [&](int buf, const XR& r) {
        uint4 w0, w1;
        w0.x = pk_bf16(r.a0.x, r.a0.y); w0.y = pk_bf16(r.a0.z, r.a0.w);
        w0.z = pk_bf16(r.b0.x, r.b0.y); w0.w = pk_bf16(r.b0.z, r.b0.w);
        w1.x = pk_bf16(r.a1.x, r.a1.y); w1.y = pk_bf16(r.a1.z, r.a1.w);
        w1.z = pk_bf16(r.b1.x, r.b1.y); w1.w = pk_bf16(r.b1.z, r.b1.w);
        char* base = wb0 + buf * 16384;
        *(uint4*)base = w0;
        *(uint4*)(base + 8192) = w1;           // row + 128
    };

    // ---- B fragment bases (frag idx = kstep*16 + wc*4 + n; 512 ushorts/frag)
    const unsigned short* bhp = Bhi + ((size_t)(wc * 4) * 64 + lane) * 8;

    // ---- A fragment addressing (const per thread except m)
    const int aoff = ((((lane >> 4) + ((lane & 15) >> 1)) & 3) << 4);
    const int arow_base = wr * 128 + (lane & 15);

    f32x4 acc[8][4];
#pragma unroll
    for (int m = 0; m < 8; ++m)
#pragma unroll
        for (int n = 0; n < 4; ++n) acc[m][n] = f32x4{0.f, 0.f, 0.f, 0.f};

    auto body = [&](int t, XR& cons, XR& iss) {
        // 1) B loads FIRST (so their wait leaves younger x loads in flight)
        const unsigned short* bhB = bhp + (size_t)t * 8192;
        bf16x8 bh[4];
#pragma unroll
        for (int n = 0; n < 4; ++n)
            bh[n] = *(const bf16x8*)(bhB + n * 512);
        // 2) x prefetch (newest vmem -> survives the B wait)
        if (t + 3 < NT) issueX(t + 3, iss);
        // 3) A frags + MFMA
        const char* ab = (const char*)lds_raw + (t & 1) * 16384;
        __builtin_amdgcn_s_setprio(1);
#pragma unroll
        for (int mm = 0; mm < 2; ++mm) {
            bf16x8 af[4];
#pragma unroll
            for (int q = 0; q < 4; ++q)
                af[q] = *(const bf16x8*)(ab + (arow_base + (mm * 4 + q) * 16) * 64 + aoff);
#pragma unroll
            for (int n = 0; n < 4; ++n)
#pragma unroll
                for (int q = 0; q < 4; ++q)
                    acc[mm * 4 + q][n] = __builtin_amdgcn_mfma_f32_16x16x32_bf16(af[q], bh[n], acc[mm * 4 + q][n], 0, 0, 0);
        }
        __builtin_amdgcn_s_setprio(0);
        // 4) stage tile t+1 into other buffer (its loads drained earlier)
        if (t < NT - 1) dswrite((t + 1) & 1, cons);
        BARRIER_LGKM();
    };

    // prologue: tile tau -> reg set tau%3; tile0 -> buf0
    issueX(0, gx0);
    issueX(1, gx1);
    dswrite(0, gx0);
    issueX(2, gx2);
    BARRIER_LGKM();

    // iter t: consumes set (t+1)%3, issues tile t+3 into set t%3
    for (int tt = 0; tt < 30; tt += 3) {
        body(tt,     gx1, gx0);
        body(tt + 1, gx2, gx1);
        body(tt + 2, gx0, gx2);
    }
    body(30, gx1, gx0);
    body(31, gx2, gx1);

    // ---- epilogue: bias + SiLU; h via LDS re-layout (coalesced stores); fused a
    float pa[32];
#pragma unroll
    for (int i = 0; i < 32; ++i) pa[i] = 0.f;

    const int rg = lane >> 4;
    float bpc[4], wac[4];
#pragma unroll
    for (int n = 0; n < 4; ++n) {
        int col = wc * 64 + n * 16 + (lane & 15);
        bpc[n] = bp[col];
        wac[n] = Wa[col];
    }

#pragma unroll
    for (int p = 0; p < 4; ++p) {              // 4 passes of 64 rows through lds_raw
        if (wr == (p >> 1)) {
#pragma unroll
            for (int q = 0; q < 4; ++q) {
                const int m = (p & 1) * 4 + q;
#pragma unroll
                for (int n = 0; n < 4; ++n) {
                    const int col = wc * 64 + n * 16 + (lane & 15);
#pragma unroll
                    for (int j = 0; j < 4; ++j) {
                        float v  = acc[m][n][j] + bpc[n];
                        float hh = v / (1.f + __expf(-v));
                        pa[m * 4 + j] = fmaf(hh, wac[n], pa[m * 4 + j]);
                        const int rl = q * 16 + rg * 4 + j;       // row within pass
                        const int byte = rl * 512 + ((col * 2) ^ (((rl >> 2) & 7) << 5));
                        *(unsigned short*)((char*)lds_raw + byte) = f2bf(hh);
                    }
                }
            }
        }
        __syncthreads();
        // coalesced copy: 64 rows x 512 B
#pragma unroll
        for (int w = 0; w < 4; ++w) {
            const int idx = w * 512 + tid;
            const int rl = idx >> 5, ch = idx & 31;
            const int lbyte = rl * 512 + ((ch * 16) ^ (((rl >> 2) & 7) << 5));
            uint4 vv = *(const uint4*)((const char*)lds_raw + lbyte);
            *(uint4*)((char*)h_out + (row0 + p * 64 + rl) * 512 + ch * 16) = vv;
        }
        __syncthreads();
    }

    // attention logits: reduce pa over the 16 lanes sharing each row
#pragma unroll
    for (int i = 0; i < 32; ++i) {
#pragma unroll
        for (int off = 1; off < 16; off <<= 1)
            pa[i] += __shfl_xor(pa[i], off, 64);
    }
    if ((lane & 15) == 0) {
#pragma unroll
        for (int m = 0; m < 8; ++m)
#pragma unroll
            for (int j = 0; j < 4; ++j)
                a_red[wc][wr * 128 + m * 16 + rg * 4 + j] = pa[m * 4 + j];
    }
    __syncthreads();
    if (tid < BM) {
        float av = a_red[0][tid] + a_red[1][tid] + a_red[2][tid] + a_red[3][tid] + ba[0];
        a_out[row0 + tid] = av;
    }
}

// ---------------------------------------------------------------------------
// Merged softmax: per-bag max + sumexp + write normalized probs p[n]
// (p = 0 beyond len). 8 blocks x 1024 threads.
// ---------------------------------------------------------------------------
__global__ __launch_bounds__(1024)
void stats_kernel(const float* __restrict__ a, const int* __restrict__ lengths,
                  float* __restrict__ p)
{
    __shared__ float red[16];
    __shared__ float bcast;
    const int b = blockIdx.x, tid = threadIdx.x;
    const int wid = tid >> 6, lane = tid & 63;
    const int len = lengths[b];
    const float* ab = a + (size_t)b * NN;

    float v[8];
    bool valid[8];
    float m = -3e38f;
#pragma unroll
    for (int i = 0; i < 8; ++i) {
        int n = tid + i * 1024;
        valid[i] = n < len;
        v[i] = valid[i] ? ab[n] : -3e38f;
        m = fmaxf(m, v[i]);
    }
    m = wave_reduce_max(m);
    if (lane == 0) red[wid] = m;
    __syncthreads();
    if (tid < 64) {
        float mm = (lane < 16) ? red[lane] : -3e38f;
        mm = wave_reduce_max(mm);
        if (lane == 0) bcast = mm;
    }
    __syncthreads();
    m = bcast;

    float e[8];
    float s = 0.f;
#pragma unroll
    for (int i = 0; i < 8; ++i) {
        e[i] = valid[i] ? expf(v[i] - m) : 0.f;
        s += e[i];
    }
    s = wave_reduce_sum(s);
    __syncthreads();
    if (lane == 0) red[wid] = s;
    __syncthreads();
    if (tid < 64) {
        float ss = (lane < 16) ? red[lane] : 0.f;
        ss = wave_reduce_sum(ss);
        if (lane == 0) bcast = ss;
    }
    __syncthreads();
    const float inv = 1.f / bcast;
#pragma unroll
    for (int i = 0; i < 8; ++i)
        p[(size_t)b * NN + tid + i * 1024] = e[i] * inv;
}

// ---------------------------------------------------------------------------
// pool: grid (32, NB) x 256 thr. Early-skip slices beyond bag length.
// ---------------------------------------------------------------------------
__global__ __launch_bounds__(256)
void pool_kernel(const unsigned short* __restrict__ h, const float* __restrict__ p,
                 const int* __restrict__ lengths, float* __restrict__ part)
{
    __shared__ float pr[4][NH];
    const int b = blockIdx.y;
    const int s = blockIdx.x;
    const int len = lengths[b];
    if (s * 256 >= len) {
        part[((size_t)b * 32 + s) * NH + threadIdx.x] = 0.f;
        return;
    }
    const int sub = threadIdx.x >> 6;
    const int cg  = threadIdx.x & 63;
    const int n0  = s * 256 + sub;

    const unsigned short* hb = h + ((size_t)b * NN + n0) * NH + cg * 4;
    const float* pb = p + (size_t)b * NN + n0;

    float ax = 0.f, ay = 0.f, az = 0.f, aw = 0.f;
#pragma unroll 8
    for (int i = 0; i < 64; ++i) {
        float pv = pb[i * 4];
        ushort4 hv = *(const ushort4*)(hb + (size_t)i * 4 * NH);
        ax = fmaf(pv, bf2f(hv.x), ax);
        ay = fmaf(pv, bf2f(hv.y), ay);
        az = fmaf(pv, bf2f(hv.z), az);
        aw = fmaf(pv, bf2f(hv.w), aw);
    }
    pr[sub][cg * 4 + 0] = ax;
    pr[sub][cg * 4 + 1] = ay;
    pr[sub][cg * 4 + 2] = az;
    pr[sub][cg * 4 + 3] = aw;
    __syncthreads();
    int c = threadIdx.x;
    part[((size_t)b * 32 + s) * NH + c] = pr[0][c] + pr[1][c] + pr[2][c] + pr[3][c];
}

// ---------------------------------------------------------------------------
// final: one block per bag. pooled = sum of 32 partials; logits = pooled@Wc+bc
// ---------------------------------------------------------------------------
__global__ void final_kernel(const float* __restrict__ part, const float* __restrict__ Wc,
                             const float* __restrict__ bc, float* __restrict__ out)
{
    __shared__ float red0[4], red1[4];
    const int b = blockIdx.x;
    const int c = threadIdx.x;
    const float wc0 = Wc[c * NC + 0], wc1 = Wc[c * NC + 1];
    const int wave = threadIdx.x >> 6, lane = threadIdx.x & 63;

    float pooled = 0.f;
#pragma unroll 8
    for (int s = 0; s < 32; ++s)
        pooled += part[((size_t)b * 32 + s) * NH + c];
    float l0 = wave_reduce_sum(pooled * wc0);
    float l1 = wave_reduce_sum(pooled * wc1);
    if (lane == 0) { red0[wave] = l0; red1[wave] = l1; }
    __syncthreads();
    if (threadIdx.x == 0) {
        out[b * NC + 0] = red0[0] + red0[1] + red0[2] + red0[3] + bc[0];
        out[b * NC + 1] = red1[0] + red1[1] + red1[2] + red1[3] + bc[1];
    }
}

extern "C" void kernel_launch(void* const* d_in, const int* in_sizes, int n_in,
                              void* d_out, int out_size, void* d_ws, size_t ws_size,
                              hipStream_t stream)
{
    const float* x       = (const float*)d_in[0];
    const int*   lengths = (const int*)d_in[1];
    const float* Wp      = (const float*)d_in[2];
    const float* bp      = (const float*)d_in[3];
    const float* Wa      = (const float*)d_in[4];
    const float* ba      = (const float*)d_in[5];
    const float* Wc      = (const float*)d_in[6];
    const float* bc      = (const float*)d_in[7];
    float* out = (float*)d_out;

    // workspace layout
    unsigned short* whi   = (unsigned short*)d_ws;            // 512 KB
    unsigned short* h_buf = whi + 262144;                     // 32 MB bf16
    float*  a_buf  = (float*)(h_buf + (size_t)M_ALL * NH);    // 256 KB
    float*  p_buf  = a_buf + M_ALL;                           // 256 KB
    float*  part   = p_buf + M_ALL;                           // 256 KB

    pack_kernel<<<128, 256, 0, stream>>>(Wp, whi);
    gemm_kernel<<<M_ALL / BM, 512, 0, stream>>>(x, whi, bp, Wa, ba, lengths, h_buf, a_buf);
    stats_kernel<<<NB, 1024, 0, stream>>>(a_buf, lengths, p_buf);
    pool_kernel<<<dim3(32, NB), 256, 0, stream>>>(h_buf, p_buf, lengths, part);
    final_kernel<<<NB, 256, 0, stream>>>(part, Wc, bc, out);
}

// Round 11
// 102.375 us; speedup vs baseline: 1.3076x; 1.3076x over previous
//
#include <hip/hip_runtime.h>
#include <hip/hip_bf16.h>
#include <math.h>

#define NB 8
#define NN 8192
#define ND 1024
#define NH 256
#define NC 2
#define M_ALL (NB * NN)   // 65536 rows
#define BM 256            // block tile rows
#define BK 32             // K per iteration
#define NT (ND / BK)      // 32 iterations
#define PSTRIDE 260       // per-tile partial: 256 pooled + m_t + l_t (+pad)

typedef __attribute__((ext_vector_type(8))) short bf16x8;
typedef __attribute__((ext_vector_type(4))) float f32x4;

// barrier WITHOUT the compiler's vmcnt(0) drain: LDS ordering only.
#define BARRIER_LGKM() asm volatile("s_waitcnt lgkmcnt(0)\n\ts_barrier" ::: "memory")

__device__ inline unsigned short f2bf(float f) {   // RNE float -> bf16 bits
    unsigned int u = __builtin_bit_cast(unsigned int, f);
    u += 0x7FFFu + ((u >> 16) & 1u);
    return (unsigned short)(u >> 16);
}
__device__ inline float bf2f(unsigned short s) {
    unsigned int u = ((unsigned int)s) << 16;
    return __builtin_bit_cast(float, u);
}
__device__ inline unsigned int pk_bf16(float a, float b) {  // low=a, high=b
    __hip_bfloat162 t = __float22bfloat162_rn(float2{a, b});
    unsigned int r;
    __builtin_memcpy(&r, &t, 4);
    return r;
}

__device__ inline float wave_reduce_sum(float v) {
#pragma unroll
    for (int off = 32; off > 0; off >>= 1) v += __shfl_down(v, off, 64);
    return v;
}
__device__ inline float wave_reduce_max(float v) {
#pragma unroll
    for (int off = 32; off > 0; off >>= 1) v = fmaxf(v, __shfl_down(v, off, 64));
    return v;
}

// ---------------------------------------------------------------------------
// Pack Wp into bf16 hi/lo, MFMA-B-fragment-contiguous:
// frag (t = kstep 0..31, f = col-frag 0..15), lane l holds
// B[k = t*32 + (l>>4)*8 + j][col = f*16 + (l&15)], j=0..7 contiguous.
// ---------------------------------------------------------------------------
__global__ void pack_kernel(const float* __restrict__ Wp,
                            unsigned short* __restrict__ hi,
                            unsigned short* __restrict__ lo)
{
    int idx  = blockIdx.x * 256 + threadIdx.x;   // 0..32767
    int lane = idx & 63;
    int f    = (idx >> 6) & 15;
    int t    = idx >> 10;
    int col  = f * 16 + (lane & 15);
    int k0   = t * 32 + (lane >> 4) * 8;
    size_t off = (size_t)idx * 8;
#pragma unroll
    for (int j = 0; j < 8; ++j) {
        float w = Wp[(size_t)(k0 + j) * NH + col];
        unsigned short h = f2bf(w);
        hi[off + j] = h;
        lo[off + j] = f2bf(w - bf2f(h));
    }
}

// ---------------------------------------------------------------------------
// Fused GEMM + SiLU + attention logit + flash-style tile pooling.
// K-loop = R7 exactly (proven 117.6): 256x256 tile, 8 waves (2 row x 4 col
// groups), BK=32, hi+lo MFMA, depth-3 x reg pipeline, vmcnt-FIFO order,
// lgkm-only barriers. Epilogue: h stays in acc regs (fp32); per-tile
// m_t = max(a), l_t = sum exp(a-m_t), pp[c] = sum exp(a-m_t) * h[:,c]
// written to part (1KB/tile). No h / a / p global round-trips.
// ---------------------------------------------------------------------------
__global__ __launch_bounds__(512, 2)
void gemm_kernel(const float* __restrict__ x,
                 const unsigned short* __restrict__ Bhi,
                 const unsigned short* __restrict__ Blo,
                 const float* __restrict__ bp,
                 const float* __restrict__ Wa,
                 const float* __restrict__ ba,
                 const int* __restrict__ lengths,
                 float* __restrict__ part)
{
    __shared__ __align__(16) unsigned char lds_raw[32768];  // A dbuf 2x16KB; reused in epilogue

    const int tid  = threadIdx.x;
    const int wave = tid >> 6;
    const int lane = tid & 63;
    const int wr = wave >> 2;           // 0..1: 128-row group
    const int wc = wave & 3;            // 0..3: 64-col group
    const int blk = blockIdx.x;
    const size_t row0 = (size_t)blk * BM;

    // ragged early-exit: this block's rows all beyond bag length
    const int bag   = blk >> 5;                // 32 blocks per bag
    const int lrow0 = (blk & 31) * BM;         // bag-local first row
    const int len   = lengths[bag];
    if (lrow0 >= len) return;

    // ---- staging geometry: thread -> 2 chunks of 8 floats (rows r0l, r0l+128)
    const int r0l = tid >> 2;                  // 0..127
    const int sl  = tid & 3;                   // chunk-in-row
    const float* xp0 = x + (row0 + r0l) * ND + sl * 8;
    const float* xp1 = xp0 + (size_t)128 * ND;
    const int offA = (((sl + (r0l >> 1)) & 3) << 4);   // rotated 16B slot
    char* const wb0 = (char*)lds_raw + r0l * 64 + offA;

    struct XR { float4 a0, b0, a1, b1; };
    XR gx0, gx1, gx2;
    auto issueX = [&](int t, XR& r) {
        const float4* p0 = (const float4*)(xp0 + (size_t)t * BK);
        const float4* p1 = (const float4*)(xp1 + (size_t)t * BK);
        r.a0 = p0[0]; r.b0 = p0[1];
        r.a1 = p1[0]; r.b1 = p1[1];
    };
    auto dswrite = [&](int buf, const XR& r) {
        uint4 w0, w1;
        w0.x = pk_bf16(r.a0.x, r.a0.y); w0.y = pk_bf16(r.a0.z, r.a0.w);
        w0.z = pk_bf16(r.b0.x, r.b0.y); w0.w = pk_bf16(r.b0.z, r.b0.w);
        w1.x = pk_bf16(r.a1.x, r.a1.y); w1.y = pk_bf16(r.a1.z, r.a1.w);
        w1.z = pk_bf16(r.b1.x, r.b1.y); w1.w = pk_bf16(r.b1.z, r.b1.w);
        char* base = wb0 + buf * 16384;
        *(uint4*)base = w0;
        *(uint4*)(base + 8192) = w1;           // row + 128
    };

    // ---- B fragment bases (frag idx = kstep*16 + wc*4 + n; 512 ushorts/frag)
    const unsigned short* bhp = Bhi + ((size_t)(wc * 4) * 64 + lane) * 8;
    const unsigned short* blp = Blo + ((size_t)(wc * 4) * 64 + lane) * 8;

    // ---- A fragment addressing (const per thread except m)
    const int aoff = ((((lane >> 4) + ((lane & 15) >> 1)) & 3) << 4);
    const int arow_base = wr * 128 + (lane & 15);

    f32x4 acc[8][4];
#pragma unroll
    for (int m = 0; m < 8; ++m)
#pragma unroll
        for (int n = 0; n < 4; ++n) acc[m][n] = f32x4{0.f, 0.f, 0.f, 0.f};

    auto body = [&](int t, XR& cons, XR& iss) {
        // 1) B loads FIRST (so their wait leaves younger x loads in flight)
        const unsigned short* bhB = bhp + (size_t)t * 8192;
        const unsigned short* blB = blp + (size_t)t * 8192;
        bf16x8 bh[4], bl[4];
#pragma unroll
        for (int n = 0; n < 4; ++n) {
            bh[n] = *(const bf16x8*)(bhB + n * 512);
            bl[n] = *(const bf16x8*)(blB + n * 512);
        }
        // 2) x prefetch (newest vmem -> survives the B wait)
        if (t + 3 < NT) issueX(t + 3, iss);
        // 3) A frags + MFMA (hi block then lo block per 4-m half)
        const char* ab = (const char*)lds_raw + (t & 1) * 16384;
        __builtin_amdgcn_s_setprio(1);
#pragma unroll
        for (int mm = 0; mm < 2; ++mm) {
            bf16x8 af[4];
#pragma unroll
            for (int q = 0; q < 4; ++q)
                af[q] = *(const bf16x8*)(ab + (arow_base + (mm * 4 + q) * 16) * 64 + aoff);
#pragma unroll
            for (int n = 0; n < 4; ++n)
#pragma unroll
                for (int q = 0; q < 4; ++q)
                    acc[mm * 4 + q][n] = __builtin_amdgcn_mfma_f32_16x16x32_bf16(af[q], bh[n], acc[mm * 4 + q][n], 0, 0, 0);
#pragma unroll
            for (int n = 0; n < 4; ++n)
#pragma unroll
                for (int q = 0; q < 4; ++q)
                    acc[mm * 4 + q][n] = __builtin_amdgcn_mfma_f32_16x16x32_bf16(af[q], bl[n], acc[mm * 4 + q][n], 0, 0, 0);
        }
        __builtin_amdgcn_s_setprio(0);
        // 4) stage tile t+1 into other buffer (its loads drained earlier)
        if (t < NT - 1) dswrite((t + 1) & 1, cons);
        BARRIER_LGKM();
    };

    // prologue: tile tau -> reg set tau%3; tile0 -> buf0
    issueX(0, gx0);
    issueX(1, gx1);
    dswrite(0, gx0);
    issueX(2, gx2);
    BARRIER_LGKM();

    // iter t: consumes set (t+1)%3, issues tile t+3 into set t%3
    for (int tt = 0; tt < 30; tt += 3) {
        body(tt,     gx1, gx0);
        body(tt + 1, gx2, gx1);
        body(tt + 2, gx0, gx2);
    }
    body(30, gx1, gx0);
    body(31, gx2, gx1);

    // =========== epilogue: SiLU in-register, logits, flash-pool ===========
    // LDS overlay (K-loop done; last barrier synchronized all):
    float* a_red  = (float*)lds_raw;            // [4][256]  4 KB
    float* a_vals = (float*)(lds_raw + 4096);   // [256]     1 KB
    float* redm   = (float*)(lds_raw + 5120);   // [8]
    float* bc2    = (float*)(lds_raw + 5152);   // [2]
    float* pp     = (float*)(lds_raw + 5248);   // [2][256]  2 KB

    const int rg = lane >> 4;
    float bpc[4], wac[4];
#pragma unroll
    for (int n = 0; n < 4; ++n) {
        int col = wc * 64 + n * 16 + (lane & 15);
        bpc[n] = bp[col];
        wac[n] = Wa[col];
    }

    // SiLU (overwrite acc with h, fp32) + per-row attention-logit partials
    float pa[32];
#pragma unroll
    for (int i = 0; i < 32; ++i) pa[i] = 0.f;
#pragma unroll
    for (int m = 0; m < 8; ++m)
#pragma unroll
        for (int n = 0; n < 4; ++n)
#pragma unroll
            for (int j = 0; j < 4; ++j) {
                float v  = acc[m][n][j] + bpc[n];
                float hh = v / (1.f + __expf(-v));
                acc[m][n][j] = hh;
                pa[m * 4 + j] = fmaf(hh, wac[n], pa[m * 4 + j]);
            }
    // reduce pa over the 16 lanes sharing each row
#pragma unroll
    for (int i = 0; i < 32; ++i) {
#pragma unroll
        for (int off = 1; off < 16; off <<= 1)
            pa[i] += __shfl_xor(pa[i], off, 64);
    }
    if ((lane & 15) == 0) {
#pragma unroll
        for (int m = 0; m < 8; ++m)
#pragma unroll
            for (int j = 0; j < 4; ++j)
                a_red[wc * BM + wr * 128 + m * 16 + rg * 4 + j] = pa[m * 4 + j];
    }
    __syncthreads();
    if (tid < BM) {
        float av = a_red[tid] + a_red[BM + tid] + a_red[2 * BM + tid] + a_red[3 * BM + tid] + ba[0];
        a_vals[tid] = (lrow0 + tid < len) ? av : -3e38f;   // mask invalid rows
    }
    __syncthreads();

    // m_t = max over valid rows
    float mv = (tid < BM) ? a_vals[tid] : -3e38f;
    mv = wave_reduce_max(mv);
    if (lane == 0) redm[wave] = mv;
    __syncthreads();
    if (tid == 0) {
        float m = redm[0];
#pragma unroll
        for (int w = 1; w < 8; ++w) m = fmaxf(m, redm[w]);
        bc2[0] = m;
    }
    __syncthreads();
    const float m_t = bc2[0];

    // l_t = sum exp(a - m_t) over valid rows (invalid -> exp(-huge)=0)
    float es = (tid < BM) ? __expf(a_vals[tid] - m_t) : 0.f;
    es = wave_reduce_sum(es);
    if (lane == 0) redm[wave] = es;
    __syncthreads();
    float l_t = 0.f;
    if (tid == 0) {
#pragma unroll
        for (int w = 0; w < 8; ++w) l_t += redm[w];
    }

    // pooled partial: pp[c] = sum_rows exp(a-m_t) * h[row][c]  (h fp32 in acc)
    float ev[32];
    const int rbase = wr * 128 + rg * 4;
#pragma unroll
    for (int m = 0; m < 8; ++m)
#pragma unroll
        for (int j = 0; j < 4; ++j)
            ev[m * 4 + j] = __expf(a_vals[rbase + m * 16 + j] - m_t);
#pragma unroll
    for (int n = 0; n < 4; ++n) {
        float s = 0.f;
#pragma unroll
        for (int m = 0; m < 8; ++m)
#pragma unroll
            for (int j = 0; j < 4; ++j)
                s = fmaf(ev[m * 4 + j], acc[m][n][j], s);
        s += __shfl_xor(s, 16, 64);
        s += __shfl_xor(s, 32, 64);
        if (lane < 16) pp[wr * 256 + wc * 64 + n * 16 + lane] = s;
    }
    __syncthreads();

    const size_t pbase = ((size_t)bag * 32 + (blk & 31)) * PSTRIDE;
    if (tid < BM) part[pbase + tid] = pp[tid] + pp[256 + tid];
    if (tid == 0) { part[pbase + 256] = m_t; part[pbase + 257] = l_t; }
}

// ---------------------------------------------------------------------------
// final: one block per bag. Flash-combine the per-tile partials, then
// logits = pooled @ Wc + bc.
// ---------------------------------------------------------------------------
__global__ __launch_bounds__(256)
void final_kernel(const float* __restrict__ part, const int* __restrict__ lengths,
                  const float* __restrict__ Wc, const float* __restrict__ bc,
                  float* __restrict__ out)
{
    __shared__ float red0[4], red1[4];
    const int b = blockIdx.x;
    const int c = threadIdx.x;
    const int len = lengths[b];
    int nt = (len + BM - 1) / BM;
    if (nt > 32) nt = 32;

    float mg = -3e38f;
    for (int t = 0; t < nt; ++t)
        mg = fmaxf(mg, part[((size_t)b * 32 + t) * PSTRIDE + 256]);

    float W = 0.f, pooled = 0.f;
    for (int t = 0; t < nt; ++t) {
        const size_t pb = ((size_t)b * 32 + t) * PSTRIDE;
        float sc = __expf(part[pb + 256] - mg);
        W      = fmaf(sc, part[pb + 257], W);
        pooled = fmaf(sc, part[pb + c],  pooled);
    }
    pooled /= W;

    const float wc0 = Wc[c * NC + 0], wc1 = Wc[c * NC + 1];
    const int wave = threadIdx.x >> 6, lane = threadIdx.x & 63;
    float l0 = wave_reduce_sum(pooled * wc0);
    float l1 = wave_reduce_sum(pooled * wc1);
    if (lane == 0) { red0[wave] = l0; red1[wave] = l1; }
    __syncthreads();
    if (threadIdx.x == 0) {
        out[b * NC + 0] = red0[0] + red0[1] + red0[2] + red0[3] + bc[0];
        out[b * NC + 1] = red1[0] + red1[1] + red1[2] + red1[3] + bc[1];
    }
}

extern "C" void kernel_launch(void* const* d_in, const int* in_sizes, int n_in,
                              void* d_out, int out_size, void* d_ws, size_t ws_size,
                              hipStream_t stream)
{
    const float* x       = (const float*)d_in[0];
    const int*   lengths = (const int*)d_in[1];
    const float* Wp      = (const float*)d_in[2];
    const float* bp      = (const float*)d_in[3];
    const float* Wa      = (const float*)d_in[4];
    const float* ba      = (const float*)d_in[5];
    const float* Wc      = (const float*)d_in[6];
    const float* bc      = (const float*)d_in[7];
    float* out = (float*)d_out;

    // workspace layout
    unsigned short* whi = (unsigned short*)d_ws;              // 512 KB
    unsigned short* wlo = whi + 262144;                       // 512 KB
    float* part = (float*)(wlo + 262144);                     // 8*32*260 f = 260 KB

    pack_kernel<<<128, 256, 0, stream>>>(Wp, whi, wlo);
    gemm_kernel<<<M_ALL / BM, 512, 0, stream>>>(x, whi, wlo, bp, Wa, ba, lengths, part);
    final_kernel<<<NB, 256, 0, stream>>>(part, lengths, Wc, bc, out);
}